// Round 21
// baseline (1924.423 us; speedup 1.0000x reference)
//
#include <hip/hip_runtime.h>
#include <hip/hip_bf16.h>

#define B_   32
#define L_   1024
#define DIN_ 9
#define DM_  512
#define NL_  4
#define DI_  1024
#define DS_  16
#define DC_  4
#define DTR_ 32
#define NC_  12
#define M_   (B_*L_)
#define NCC_ 2              // batch chunks
#define MC_  (M_/NCC_)
#define BC_  (B_/NCC_)
#define NCH_ 32             // scan chunks per sequence
#define CHT_ 32             // L_/NCH_

typedef unsigned short u16;
typedef __attribute__((ext_vector_type(8))) short bf16x8;
typedef __attribute__((ext_vector_type(4))) float f32x4;

__device__ __forceinline__ float bf2f(u16 h){
  union { unsigned int u; float f; } v; v.u = ((unsigned int)h) << 16; return v.f;
}
__device__ __forceinline__ u16 f2bf(float f){
  union { float f; unsigned int u; } v; v.f = f;
  unsigned int u = v.u;
  return (u16)((u + 0x7fffu + ((u >> 16) & 1u)) >> 16);
}
// SiLU via 1-ulp v_rcp_f32 (validated round 13: absmax 1.24e-5)
__device__ __forceinline__ float siluf(float x){
  return x * __builtin_amdgcn_rcpf(1.f + __expf(-x));
}

// ---- async global->LDS, 16B per lane; LDS dest is wave-uniform base + lane*16 ----
__device__ __forceinline__ void gload_lds16(const u16* g, u16* l){
  __builtin_amdgcn_global_load_lds(
      (const __attribute__((address_space(1))) void*)(unsigned long long)(const void*)g,
      (__attribute__((address_space(3))) void*)(unsigned int)(unsigned long long)(void*)l,
      16, 0, 0);
}

// -------- one-shot weight cast fp32 -> bf16 (w_in, w_out, xpw, dtw) --------
#define NW1_ (NL_*2*DI_*DM_)
#define NW3_ (NL_*DM_*DI_)
#define NW2_ (NL_*64*DI_)
#define NW4_ (NL_*DI_*DTR_)
__global__ __launch_bounds__(256) void cast4_kernel(const float* __restrict__ a,
                                                    const float* __restrict__ c,
                                                    const float* __restrict__ e,
                                                    const float* __restrict__ f,
                                                    u16* __restrict__ oa,
                                                    u16* __restrict__ oc,
                                                    u16* __restrict__ oe,
                                                    u16* __restrict__ of){
  int i = blockIdx.x * 256 + threadIdx.x;
  if (i < NW1_) oa[i] = f2bf(a[i]);
  else if (i < NW1_ + NW3_) oc[i - NW1_] = f2bf(c[i - NW1_]);
  else if (i < NW1_ + NW3_ + NW2_) oe[i - NW1_ - NW3_] = f2bf(e[i - NW1_ - NW3_]);
  else if (i < NW1_ + NW3_ + NW2_ + NW4_)
    of[i - NW1_ - NW3_ - NW2_] = f2bf(f[i - NW1_ - NW3_ - NW2_]);
}

// --------- prep: transpose conv weights [l][e][4]->[l][4][e], A_log -> -exp, [l][s][e]
__global__ __launch_bounds__(256) void prep_kernel(const float* __restrict__ convw,
                                                   const float* __restrict__ A_log,
                                                   float* __restrict__ cwt,
                                                   float* __restrict__ At){
  int gid = blockIdx.x * 256 + threadIdx.x;      // NL_*DI_
  int l = gid >> 10, e = gid & (DI_ - 1);
  float4 cw = *(const float4*)(convw + (size_t)gid * 4);
  cwt[(l * 4 + 0) * DI_ + e] = cw.x;
  cwt[(l * 4 + 1) * DI_ + e] = cw.y;
  cwt[(l * 4 + 2) * DI_ + e] = cw.z;
  cwt[(l * 4 + 3) * DI_ + e] = cw.w;
  const float* ar = A_log + (size_t)gid * DS_;
#pragma unroll
  for (int s = 0; s < DS_; s++)
    At[((size_t)l * DS_ + s) * DI_ + e] = -__expf(ar[s]);
}

// ------- input projection: h = bf16(x @ ip_w^T + ip_b); w register-cached -------
__global__ __launch_bounds__(256) void inproj_kernel(const float* __restrict__ x,
                                                     const float* __restrict__ w,
                                                     const float* __restrict__ bias,
                                                     u16* __restrict__ h){
  __shared__ float xs[32 * DIN_];
  const int tid = threadIdx.x;
  const int m0 = blockIdx.x * 32;
  for (int i = tid; i < 32 * DIN_; i += 256) xs[i] = x[(size_t)m0 * DIN_ + i];
  float w0[DIN_], w1[DIN_];
  const int d0 = tid * 2;
#pragma unroll
  for (int i = 0; i < DIN_; i++){
    w0[i] = w[(size_t)d0 * DIN_ + i];
    w1[i] = w[(size_t)(d0 + 1) * DIN_ + i];
  }
  const float b0 = bias[d0], b1 = bias[d0 + 1];
  __syncthreads();
  for (int r = 0; r < 32; r++){
    float a0 = b0, a1 = b1;
    const float* xr = &xs[r * DIN_];
#pragma unroll
    for (int i = 0; i < DIN_; i++){
      float xv = xr[i];
      a0 = fmaf(xv, w0[i], a0);
      a1 = fmaf(xv, w1[i], a1);
    }
    unsigned int pk = ((unsigned int)f2bf(a1) << 16) | (unsigned int)f2bf(a0);
    *(unsigned int*)(h + (size_t)(m0 + r) * DM_ + d0) = pk;
  }
}

// ---------------- fused layernorm: bf16 h -> bf16 hn (stats + apply) ----------------
__global__ __launch_bounds__(256) void ln_kernel(const u16* __restrict__ h,
                                                 const float* __restrict__ g,
                                                 const float* __restrict__ bt,
                                                 u16* __restrict__ hn){
  int row = blockIdx.x * 4 + (threadIdx.x >> 6);
  int lane = threadIdx.x & 63;
  const u16* hr = h + (size_t)row * DM_ + lane * 8;
  ushort4 a0 = *(const ushort4*)(hr);
  ushort4 a1 = *(const ushort4*)(hr + 4);
  float v[8];
  v[0]=bf2f(a0.x); v[1]=bf2f(a0.y); v[2]=bf2f(a0.z); v[3]=bf2f(a0.w);
  v[4]=bf2f(a1.x); v[5]=bf2f(a1.y); v[6]=bf2f(a1.z); v[7]=bf2f(a1.w);
  float s = 0.f, q = 0.f;
#pragma unroll
  for (int i = 0; i < 8; i++){ s += v[i]; q += v[i]*v[i]; }
#pragma unroll
  for (int o = 32; o; o >>= 1){ s += __shfl_xor(s, o); q += __shfl_xor(q, o); }
  float mean = s * (1.f / DM_);
  float rstd = rsqrtf(q * (1.f / DM_) - mean * mean + 1e-5f);
  float4 g0 = *(const float4*)(g + lane * 8);
  float4 g1 = *(const float4*)(g + lane * 8 + 4);
  float4 b0 = *(const float4*)(bt + lane * 8);
  float4 b1 = *(const float4*)(bt + lane * 8 + 4);
  ushort4 o0, o1;
  o0.x = f2bf((v[0]-mean)*rstd*g0.x + b0.x);
  o0.y = f2bf((v[1]-mean)*rstd*g0.y + b0.y);
  o0.z = f2bf((v[2]-mean)*rstd*g0.z + b0.z);
  o0.w = f2bf((v[3]-mean)*rstd*g0.w + b0.w);
  o1.x = f2bf((v[4]-mean)*rstd*g1.x + b1.x);
  o1.y = f2bf((v[5]-mean)*rstd*g1.y + b1.y);
  o1.z = f2bf((v[6]-mean)*rstd*g1.z + b1.z);
  o1.w = f2bf((v[7]-mean)*rstd*g1.w + b1.w);
  u16* op = hn + (size_t)row * DM_ + lane * 8;
  *(ushort4*)(op)     = o0;
  *(ushort4*)(op + 4) = o1;
}

// ------- causal depthwise conv (DC=4) + SiLU, 8 ch/thread, transposed weights ------
__global__ __launch_bounds__(256) void conv8_kernel(const u16* __restrict__ xu,
                                                    const float* __restrict__ cwt,
                                                    const float* __restrict__ cbp,
                                                    u16* __restrict__ ub){
  int idx = blockIdx.x * 256 + threadIdx.x;      // over MC*DI/8
  int e8 = (idx & 127) * 8;
  int bl = idx >> 7;
  int l = bl & (L_ - 1);
  const u16* p = xu + (size_t)bl * DI_ + e8;
  float acc[8];
  {
    float4 c0 = *(const float4*)(cbp + e8);
    float4 c1 = *(const float4*)(cbp + e8 + 4);
    acc[0]=c0.x; acc[1]=c0.y; acc[2]=c0.z; acc[3]=c0.w;
    acc[4]=c1.x; acc[5]=c1.y; acc[6]=c1.z; acc[7]=c1.w;
  }
#pragma unroll
  for (int d = 0; d < 4; d++){
    if (l - 3 + d >= 0){
      const u16* q = p - (size_t)(3 - d) * DI_;
      ushort4 v0 = *(const ushort4*)q, v1 = *(const ushort4*)(q + 4);
      float4 w0 = *(const float4*)(cwt + d * DI_ + e8);
      float4 w1 = *(const float4*)(cwt + d * DI_ + e8 + 4);
      acc[0] += bf2f(v0.x) * w0.x; acc[1] += bf2f(v0.y) * w0.y;
      acc[2] += bf2f(v0.z) * w0.z; acc[3] += bf2f(v0.w) * w0.w;
      acc[4] += bf2f(v1.x) * w1.x; acc[5] += bf2f(v1.y) * w1.y;
      acc[6] += bf2f(v1.z) * w1.z; acc[7] += bf2f(v1.w) * w1.w;
    }
  }
  ushort4 h0, h1;
  h0.x = f2bf(siluf(acc[0])); h0.y = f2bf(siluf(acc[1]));
  h0.z = f2bf(siluf(acc[2])); h0.w = f2bf(siluf(acc[3]));
  h1.x = f2bf(siluf(acc[4])); h1.y = f2bf(siluf(acc[5]));
  h1.z = f2bf(siluf(acc[6])); h1.w = f2bf(siluf(acc[7]));
  u16* o = ub + (size_t)bl * DI_ + e8;
  *(ushort4*)o = h0;
  *(ushort4*)(o + 4) = h1;
}

// ---------------- GEMM: C[M][N] = A[M][K] (bf16) @ W[N][K]^T (bf16) ----------------
// TPB threads. global_load_lds staging (linear LDS dest + pre-swizzled source), swz
// read. 1D grid with XCD-locality swizzle. Direct scalar C stores (proven fastest
// tail for this 2-barrier structure; LDS-staged and packed variants both regressed).
// EPI 0: bf16 store. EPI 1: bf16(softplus(v + bias[n])). EPI 2: bf16(v + Res)
// (Cb may alias Res). EPI 4: n<nsplit -> Cb raw, else Cb2 silu (stride nsplit).
template<int BM, int BN, int BK, int EPI, int TPB>
__global__ __launch_bounds__(TPB)
void gemm_bt(const u16* __restrict__ A, int lda,
             const u16* __restrict__ Bw,
             u16* Cb, u16* Cb2, const u16* Res,
             const float* __restrict__ bias,
             int N, int K, int nsplit, int gx){
  constexpr int CH = BK / 8;
  constexpr int MASK = CH - 1;
  constexpr int WROWS = TPB / 128;     // 2 or 4
  constexpr int WM = BM / WROWS, WN = BN / 2;
  constexpr int FM = WM / 16, FN = WN / 16;
  __shared__ u16 As_[BM * BK];
  __shared__ u16 Bs_[BN * BK];
  const int tid = threadIdx.x;
  const int lane = tid & 63;
  const int wid = tid >> 6;
  const int wr = wid >> 1, wc = wid & 1;
  int bm, bn;
  {
    const int wg = blockIdx.x;
    const int gy = (int)gridDim.x / gx;
    const int ypx = gy >> 3;            // M-panels per XCD
    const int xcd = wg & 7;
    const int idx = wg >> 3;
    const int y = xcd * ypx + (idx % ypx);
    const int x = idx / ypx;
    bm = y * BM; bn = x * BN;
  }
  f32x4 acc[FM][FN];
#pragma unroll
  for (int i = 0; i < FM; i++)
#pragma unroll
    for (int j = 0; j < FN; j++) acc[i][j] = f32x4{0.f, 0.f, 0.f, 0.f};
  constexpr int LA = BM * BK / (TPB * 8);
  constexpr int LB = BN * BK / (TPB * 8);
  const int wbase = wid * 64;           // wave-uniform chunk base within a TPB-group
  for (int k0 = 0; k0 < K; k0 += BK){
    __syncthreads();
#pragma unroll
    for (int i = 0; i < LA; i++){
      int chunk = i * TPB + tid;
      int row = chunk / CH, cs = chunk & MASK;
      int cg = cs ^ (row & MASK);       // pre-swizzled global source chunk
      const u16* g = A + (size_t)(bm + row) * lda + k0 + cg * 8;
      gload_lds16(g, &As_[(i * TPB + wbase) * 8]);
    }
#pragma unroll
    for (int i = 0; i < LB; i++){
      int chunk = i * TPB + tid;
      int row = chunk / CH, cs = chunk & MASK;
      int cg = cs ^ (row & MASK);
      const u16* g = Bw + (size_t)(bn + row) * K + k0 + cg * 8;
      gload_lds16(g, &Bs_[(i * TPB + wbase) * 8]);
    }
    __syncthreads();
#pragma unroll
    for (int kk = 0; kk < BK / 32; kk++){
      bf16x8 af[FM], bfr[FN];
      const int kch = kk * 4 + (lane >> 4);
#pragma unroll
      for (int mi = 0; mi < FM; mi++){
        int r = wr * WM + mi * 16 + (lane & 15);
        af[mi] = *(const bf16x8*)(&As_[r * BK + ((kch ^ (r & MASK))) * 8]);
      }
#pragma unroll
      for (int ni = 0; ni < FN; ni++){
        int r = wc * WN + ni * 16 + (lane & 15);
        bfr[ni] = *(const bf16x8*)(&Bs_[r * BK + ((kch ^ (r & MASK))) * 8]);
      }
#pragma unroll
      for (int mi = 0; mi < FM; mi++)
#pragma unroll
        for (int ni = 0; ni < FN; ni++)
          acc[mi][ni] = __builtin_amdgcn_mfma_f32_16x16x32_bf16(af[mi], bfr[ni], acc[mi][ni], 0, 0, 0);
    }
  }
  const int rq = (lane >> 4) * 4, cl = lane & 15;
#pragma unroll
  for (int mi = 0; mi < FM; mi++){
#pragma unroll
    for (int ni = 0; ni < FN; ni++){
      const int n = bn + wc * WN + ni * 16 + cl;
#pragma unroll
      for (int j = 0; j < 4; j++){
        const int m = bm + wr * WM + mi * 16 + rq + j;
        float v = acc[mi][ni][j];
        if constexpr (EPI == 0){
          Cb[(size_t)m * N + n] = f2bf(v);
        } else if constexpr (EPI == 1){
          float xx = v + bias[n];
          float sp = (xx > 20.f) ? xx : __logf(1.f + __expf(xx));
          Cb[(size_t)m * N + n] = f2bf(sp);
        } else if constexpr (EPI == 2){
          const size_t off = (size_t)m * N + n;
          Cb[off] = f2bf(v + bf2f(Res[off]));
        } else {
          if (n < nsplit){
            Cb[(size_t)m * nsplit + n] = f2bf(v);
          } else {
            Cb2[(size_t)m * nsplit + (n - nsplit)] = f2bf(siluf(v));
          }
        }
      }
    }
  }
}

// ---------------- scan pass 1: per-chunk (sdd, h_part), h0 = 0 ----------------
// grid (DI/256, NCH, Bc); sdd_b[c][be] f32; h_b[c][be][16] f32
__global__ __launch_bounds__(256)
void scan1_kernel(const u16* __restrict__ ub, const u16* __restrict__ dlt,
                  const u16* __restrict__ xdb,
                  const float* __restrict__ At,
                  float* __restrict__ sdd_b, float* __restrict__ h_b){
  const int tid = threadIdx.x;
  const int e = blockIdx.x * 256 + tid;
  const int c = blockIdx.y, b = blockIdx.z;
  __shared__ float Bsh[CHT_][DS_];     // 2 KB
  if (tid < CHT_ * DS_ / 4){
    int row = tid >> 2, col4 = (tid & 3) * 4;
    const u16* p = xdb + ((size_t)b * L_ + (size_t)c * CHT_ + row) * 64 + 32 + col4;
    ushort4 v = *(const ushort4*)p;
    Bsh[row][col4+0] = bf2f(v.x); Bsh[row][col4+1] = bf2f(v.y);
    Bsh[row][col4+2] = bf2f(v.z); Bsh[row][col4+3] = bf2f(v.w);
  }
  __syncthreads();
  float As[DS_];
  bool fast = true;
#pragma unroll
  for (int s = 0; s < DS_; s++){
    As[s] = At[(size_t)s * DI_ + e];
    fast = fast && (fabsf(As[s] + (float)(s + 1)) <= 1e-3f * (s + 1));
  }
  float h[DS_];
#pragma unroll
  for (int s = 0; s < DS_; s++) h[s] = 0.f;
  float sdd = 0.f;
  const size_t base = ((size_t)b * L_ + (size_t)c * CHT_) * DI_ + e;
  if (fast){
    for (int t = 0; t < CHT_; t++){
      const size_t idx = base + (size_t)t * DI_;
      float ut = bf2f(ub[idx]);
      float delta = bf2f(dlt[idx]);
      sdd += delta;
      float du = delta * ut;
      float e1 = __expf(-delta);
      float e2 = e1*e1, e4 = e2*e2, e8 = e4*e4;
      float dA[DS_] = {e1, e2, e2*e1, e4, e4*e1, e4*e2, e4*e2*e1, e8,
                       e8*e1, e8*e2, e8*e2*e1, e8*e4, e8*e4*e1, e8*e4*e2,
                       e8*e4*e2*e1, e8*e8};
      const float* r = &Bsh[t][0];
#pragma unroll
      for (int s = 0; s < DS_; s++)
        h[s] = fmaf(dA[s], h[s], du * r[s]);
    }
  } else {
    for (int t = 0; t < CHT_; t++){
      const size_t idx = base + (size_t)t * DI_;
      float ut = bf2f(ub[idx]);
      float delta = bf2f(dlt[idx]);
      sdd += delta;
      float du = delta * ut;
      const float* r = &Bsh[t][0];
#pragma unroll
      for (int s = 0; s < DS_; s++)
        h[s] = fmaf(__expf(delta * As[s]), h[s], du * r[s]);
    }
  }
  const size_t be = (size_t)b * DI_ + e;
  sdd_b[(size_t)c * (BC_ * DI_) + be] = sdd;
  float* p = h_b + ((size_t)c * (BC_ * DI_) + be) * DS_;
#pragma unroll
  for (int s = 0; s < DS_; s++) p[s] = h[s];
}

// -------- scan pass 2: combine (a_prod recomputed from sdd) -> h_init per chunk -----
__global__ __launch_bounds__(256)
void scan2_kernel(const float* __restrict__ At,
                  const float* __restrict__ sdd_b, float* __restrict__ h_b){
  const int be = blockIdx.x * 256 + threadIdx.x;
  const int BE = BC_ * DI_;
  const int e = be & (DI_ - 1);
  float As[DS_];
  bool fast = true;
#pragma unroll
  for (int s = 0; s < DS_; s++){
    As[s] = At[(size_t)s * DI_ + e];
    fast = fast && (fabsf(As[s] + (float)(s + 1)) <= 1e-3f * (s + 1));
  }
  float h[DS_];
#pragma unroll
  for (int s = 0; s < DS_; s++) h[s] = 0.f;
  for (int c = 0; c < NCH_; c++){
    float sdd = sdd_b[(size_t)c * BE + be];
    float* p = h_b + ((size_t)c * BE + be) * DS_;
    float4 h0 = *(const float4*)(p);
    float4 h1 = *(const float4*)(p + 4);
    float4 h2 = *(const float4*)(p + 8);
    float4 h3 = *(const float4*)(p + 12);
    float hv[16] = {h0.x,h0.y,h0.z,h0.w, h1.x,h1.y,h1.z,h1.w,
                    h2.x,h2.y,h2.z,h2.w, h3.x,h3.y,h3.z,h3.w};
    float ap[DS_];
    if (fast){
      float e1 = __expf(-sdd);
      float e2 = e1*e1, e4 = e2*e2, e8 = e4*e4;
      ap[0]=e1; ap[1]=e2; ap[2]=e2*e1; ap[3]=e4; ap[4]=e4*e1; ap[5]=e4*e2;
      ap[6]=e4*e2*e1; ap[7]=e8; ap[8]=e8*e1; ap[9]=e8*e2; ap[10]=e8*e2*e1;
      ap[11]=e8*e4; ap[12]=e8*e4*e1; ap[13]=e8*e4*e2; ap[14]=e8*e4*e2*e1;
      ap[15]=e8*e8;
    } else {
#pragma unroll
      for (int s = 0; s < DS_; s++) ap[s] = __expf(As[s] * sdd);
    }
    float4 w0, w1, w2, w3;
    float* wv[4] = {&w0.x, &w1.x, &w2.x, &w3.x};
#pragma unroll
    for (int s = 0; s < DS_; s++){
      float hi = h[s];
      h[s] = ap[s] * hi + hv[s];
      wv[s >> 2][s & 3] = hi;
    }
    *(float4*)(p)      = w0;
    *(float4*)(p + 4)  = w1;
    *(float4*)(p + 8)  = w2;
    *(float4*)(p + 12) = w3;
  }
}

// ---------------- scan pass 3: rescan + gate; y over silu(z) in place --------------
__global__ __launch_bounds__(256)
void scan3_kernel(const u16* __restrict__ ub, const u16* __restrict__ dlt,
                  u16* __restrict__ zy, const u16* __restrict__ xdb,
                  const float* __restrict__ At, const float* __restrict__ Dp,
                  const float* __restrict__ h_b){
  const int tid = threadIdx.x;
  const int e = blockIdx.x * 256 + tid;
  const int c = blockIdx.y, b = blockIdx.z;
  __shared__ float BC[CHT_][32];       // 4 KB: B | C
  {
    int row = tid >> 3, col4 = (tid & 7) * 4;
    const u16* p = xdb + ((size_t)b * L_ + (size_t)c * CHT_ + row) * 64 + 32 + col4;
    ushort4 v = *(const ushort4*)p;
    BC[row][col4+0] = bf2f(v.x); BC[row][col4+1] = bf2f(v.y);
    BC[row][col4+2] = bf2f(v.z); BC[row][col4+3] = bf2f(v.w);
  }
  __syncthreads();
  float As[DS_];
  bool fast = true;
#pragma unroll
  for (int s = 0; s < DS_; s++){
    As[s] = At[(size_t)s * DI_ + e];
    fast = fast && (fabsf(As[s] + (float)(s + 1)) <= 1e-3f * (s + 1));
  }
  const float Dv = Dp[e];
  const float* ip = h_b + ((size_t)c * (BC_ * DI_) + (size_t)b * DI_ + e) * DS_;
  float h[DS_];
#pragma unroll
  for (int s = 0; s < DS_; s++) h[s] = ip[s];
  const size_t base = ((size_t)b * L_ + (size_t)c * CHT_) * DI_ + e;
  if (fast){
    for (int t = 0; t < CHT_; t++){
      const size_t idx = base + (size_t)t * DI_;
      float ut = bf2f(ub[idx]);
      float delta = bf2f(dlt[idx]);
      float du = delta * ut;
      float e1 = __expf(-delta);
      float e2 = e1*e1, e4 = e2*e2, e8 = e4*e4;
      float dA[DS_] = {e1, e2, e2*e1, e4, e4*e1, e4*e2, e4*e2*e1, e8,
                       e8*e1, e8*e2, e8*e2*e1, e8*e4, e8*e4*e1, e8*e4*e2,
                       e8*e4*e2*e1, e8*e8};
      const float* r = &BC[t][0];
      float yv = 0.f;
#pragma unroll
      for (int s = 0; s < DS_; s++){
        h[s] = fmaf(dA[s], h[s], du * r[s]);
        yv = fmaf(h[s], r[16 + s], yv);
      }
      float zs = bf2f(zy[idx]);
      zy[idx] = f2bf((yv + ut * Dv) * zs);
    }
  } else {
    for (int t = 0; t < CHT_; t++){
      const size_t idx = base + (size_t)t * DI_;
      float ut = bf2f(ub[idx]);
      float delta = bf2f(dlt[idx]);
      float du = delta * ut;
      const float* r = &BC[t][0];
      float yv = 0.f;
#pragma unroll
      for (int s = 0; s < DS_; s++){
        h[s] = fmaf(__expf(delta * As[s]), h[s], du * r[s]);
        yv = fmaf(h[s], r[16 + s], yv);
      }
      float zs = bf2f(zy[idx]);
      zy[idx] = f2bf((yv + ut * Dv) * zs);
    }
  }
}

// ---------------- mean-pool partials over L ----------------
__global__ __launch_bounds__(256) void pool_kernel(const u16* __restrict__ h,
                                                   float* __restrict__ part){
  int d = blockIdx.x * 256 + threadIdx.x;
  int b = blockIdx.y;
  int p = blockIdx.z;
  float s = 0.f;
  const u16* hp = h + ((size_t)b * L_ + p * 128) * DM_ + d;
  for (int l = 0; l < 128; l++) s += bf2f(hp[(size_t)l * DM_]);
  part[((size_t)p * B_ + b) * DM_ + d] = s;
}

// ---------------- final FC ----------------
__global__ __launch_bounds__(256) void fc_kernel(const float* __restrict__ part,
                                                 const float* __restrict__ fcw,
                                                 const float* __restrict__ fcb,
                                                 float* __restrict__ out){
  int b = blockIdx.x;
  int tid = threadIdx.x;
  __shared__ float pd[DM_];
  for (int d = tid; d < DM_; d += 256){
    float s = 0.f;
    for (int p = 0; p < 8; p++) s += part[((size_t)p * B_ + b) * DM_ + d];
    pd[d] = s * (1.f / L_);
  }
  __syncthreads();
  int wid = tid >> 6, lane = tid & 63;
  for (int c = wid; c < NC_; c += 4){
    float s = 0.f;
    for (int d = lane; d < DM_; d += 64) s += pd[d] * fcw[c * DM_ + d];
#pragma unroll
    for (int o = 32; o; o >>= 1) s += __shfl_xor(s, o);
    if (lane == 0) out[b * NC_ + c] = s + fcb[c];
  }
}

extern "C" void kernel_launch(void* const* d_in, const int* in_sizes, int n_in,
                              void* d_out, int out_size, void* d_ws, size_t ws_size,
                              hipStream_t stream){
  const float* x     = (const float*)d_in[0];
  const float* ip_w  = (const float*)d_in[1];
  const float* ip_b  = (const float*)d_in[2];
  const float* ln_g  = (const float*)d_in[3];
  const float* ln_b  = (const float*)d_in[4];
  const float* inpw  = (const float*)d_in[5];
  const float* convw = (const float*)d_in[6];
  const float* convb = (const float*)d_in[7];
  const float* xpw   = (const float*)d_in[8];
  const float* dtw   = (const float*)d_in[9];
  const float* dtb   = (const float*)d_in[10];
  const float* Alog  = (const float*)d_in[11];
  const float* Dp    = (const float*)d_in[12];
  const float* outw  = (const float*)d_in[13];
  const float* fcw   = (const float*)d_in[14];
  const float* fcb   = (const float*)d_in[15];
  float* out = (float*)d_out;

  char* ws = (char*)d_ws;
  size_t off = 0;
  auto alloc = [&](size_t bytes) -> void* {
    void* p = ws + off; off += (bytes + 255) & ~(size_t)255; return p;
  };
  // total ~212 MB (ws_size >= ~217 MB established in round 8; < 238 from round 4)
  u16*    h16   = (u16*)   alloc((size_t)M_ * DM_ * 2);          // 32 MB
  float*  part  = (float*) alloc((size_t)8 * B_ * DM_ * 4);      // 0.5 MB
  u16*    w_in  = (u16*)   alloc((size_t)NW1_ * 2);              // 8.4 MB
  u16*    w_out = (u16*)   alloc((size_t)NW3_ * 2);              // 4.2 MB
  u16*    w_xp  = (u16*)   alloc((size_t)NW2_ * 2);              // 0.5 MB
  u16*    w_dt  = (u16*)   alloc((size_t)NW4_ * 2);              // 0.26 MB
  float*  cwt   = (float*) alloc((size_t)NL_ * 4 * DI_ * 4);     // 64 KB
  float*  At    = (float*) alloc((size_t)NL_ * DS_ * DI_ * 4);   // 256 KB
  u16*    xu    = (u16*)   alloc((size_t)MC_ * DI_ * 2);         // 32 MB u_pre
  u16*    ub    = (u16*)   alloc((size_t)MC_ * DI_ * 2);         // 32 MB u
  u16*    xzs   = (u16*)   alloc((size_t)MC_ * DI_ * 2);         // 32 MB silu(z)->y
  u16*    dlt   = (u16*)   alloc((size_t)MC_ * DI_ * 2);         // 32 MB hn, then delta
  u16*    xdb   = (u16*)   alloc((size_t)MC_ * 64 * 2);          // 2 MB dt_in|B|C
  float*  sddb  = (float*) alloc((size_t)NCH_ * BC_ * DI_ * 4);      // 2 MB
  float*  hb    = (float*) alloc((size_t)NCH_ * BC_ * DI_ * DS_ * 4); // 33.5 MB
  u16*    hn    = dlt;     // alias: hn lives in dlt until dt GEMM overwrites it

  cast4_kernel<<<(NW1_ + NW3_ + NW2_ + NW4_ + 255) / 256, 256, 0, stream>>>(
      inpw, outw, xpw, dtw, w_in, w_out, w_xp, w_dt);
  prep_kernel<<<(NL_ * DI_) / 256, 256, 0, stream>>>(convw, Alog, cwt, At);
  inproj_kernel<<<M_ / 32, 256, 0, stream>>>(x, ip_w, ip_b, h16);

  const int GY64 = MC_ / 64;  // 256 M-panels (64-row tiles; multiple of 8)
  const int GY2  = MC_ / 256; // 64 M-panels (256-row tiles; multiple of 8)
  for (int i = 0; i < NL_; i++){
    const float* At_l = At + (size_t)i * DS_ * DI_;
    for (int c = 0; c < NCC_; c++){
      u16* hc = h16 + (size_t)c * MC_ * DM_;

      // fused LN (stats + apply), hn materialized in dlt buffer
      ln_kernel<<<MC_ / 4, 256, 0, stream>>>(hc, ln_g + i * DM_, ln_b + i * DM_, hn);

      // in-proj 256x128 tile, 512 thr; split epi: xu = u_pre, xzs = silu(z) (gx=16)
      gemm_bt<256, 128, 64, 4, 512><<<16 * GY2, 512, 0, stream>>>(
          hn, DM_, w_in + (size_t)i * 2 * DI_ * DM_, xu, xzs, nullptr, nullptr,
          2 * DI_, DM_, DI_, 16);

      // u = silu(causal_conv(u_pre)), transposed weights, materialized once
      conv8_kernel<<<(MC_ * DI_ / 8) / 256, 256, 0, stream>>>(
          xu, cwt + (size_t)i * 4 * DI_, convb + i * DI_, ub);

      // x_dbl = u @ xpw^T  (N=64: dt_in | B | C)  64-row tile -> 256 blocks (gx=1)
      gemm_bt<64, 64, 64, 0, 256><<<1 * GY64, 256, 0, stream>>>(
          ub, DI_, w_xp + (size_t)i * 64 * DI_, xdb, nullptr, nullptr, nullptr,
          64, DI_, 0, 1);

      // delta = softplus(x_dbl[:, :32] @ dtw^T + dt_b)  256x128, 512 thr (gx=8)
      gemm_bt<256, 128, 32, 1, 512><<<8 * GY2, 512, 0, stream>>>(
          xdb, 64, w_dt + (size_t)i * DI_ * DTR_, dlt, nullptr, nullptr,
          dtb + i * DI_, DI_, DTR_, 0, 8);

      // chunk-parallel scan (NCH=32 -> 2048 blocks, 8 waves/SIMD)
      scan1_kernel<<<dim3(DI_ / 256, NCH_, BC_), 256, 0, stream>>>(
          ub, dlt, xdb, At_l, sddb, hb);
      scan2_kernel<<<(BC_ * DI_) / 256, 256, 0, stream>>>(At_l, sddb, hb);
      scan3_kernel<<<dim3(DI_ / 256, NCH_, BC_), 256, 0, stream>>>(
          ub, dlt, xzs, xdb, At_l, Dp + i * DI_, hb);

      // h += y_gated @ out_w^T  256x128 tile (gx = 4)
      gemm_bt<256, 128, 64, 2, 512><<<4 * GY2, 512, 0, stream>>>(
          xzs, DI_, w_out + (size_t)i * DM_ * DI_, hc, nullptr, hc,
          nullptr, DM_, DI_, 0, 4);
    }
  }

  pool_kernel<<<dim3(2, B_, 8), 256, 0, stream>>>(h16, part);
  fc_kernel<<<B_, 256, 0, stream>>>(part, fcw, fcb, out);
}

// Round 22
// 1914.597 us; speedup vs baseline: 1.0051x; 1.0051x over previous
//
#include <hip/hip_runtime.h>
#include <hip/hip_bf16.h>

#define B_   32
#define L_   1024
#define DIN_ 9
#define DM_  512
#define NL_  4
#define DI_  1024
#define DS_  16
#define DC_  4
#define DTR_ 32
#define NC_  12
#define M_   (B_*L_)
#define NCC_ 2              // batch chunks
#define MC_  (M_/NCC_)
#define BC_  (B_/NCC_)
#define NCH_ 32             // scan chunks per sequence
#define CHT_ 32             // L_/NCH_

typedef unsigned short u16;
typedef __attribute__((ext_vector_type(8))) short bf16x8;
typedef __attribute__((ext_vector_type(4))) float f32x4;

__device__ __forceinline__ float bf2f(u16 h){
  union { unsigned int u; float f; } v; v.u = ((unsigned int)h) << 16; return v.f;
}
__device__ __forceinline__ u16 f2bf(float f){
  union { float f; unsigned int u; } v; v.f = f;
  unsigned int u = v.u;
  return (u16)((u + 0x7fffu + ((u >> 16) & 1u)) >> 16);
}
// SiLU via 1-ulp v_rcp_f32 (validated round 13: absmax 1.24e-5)
__device__ __forceinline__ float siluf(float x){
  return x * __builtin_amdgcn_rcpf(1.f + __expf(-x));
}

// ---- async global->LDS, 16B per lane; LDS dest is wave-uniform base + lane*16 ----
__device__ __forceinline__ void gload_lds16(const u16* g, u16* l){
  __builtin_amdgcn_global_load_lds(
      (const __attribute__((address_space(1))) void*)(unsigned long long)(const void*)g,
      (__attribute__((address_space(3))) void*)(unsigned int)(unsigned long long)(void*)l,
      16, 0, 0);
}

// -------- one-shot weight cast fp32 -> bf16 (w_in, w_out, xpw, dtw) --------
#define NW1_ (NL_*2*DI_*DM_)
#define NW3_ (NL_*DM_*DI_)
#define NW2_ (NL_*64*DI_)
#define NW4_ (NL_*DI_*DTR_)
__global__ __launch_bounds__(256) void cast4_kernel(const float* __restrict__ a,
                                                    const float* __restrict__ c,
                                                    const float* __restrict__ e,
                                                    const float* __restrict__ f,
                                                    u16* __restrict__ oa,
                                                    u16* __restrict__ oc,
                                                    u16* __restrict__ oe,
                                                    u16* __restrict__ of){
  int i = blockIdx.x * 256 + threadIdx.x;
  if (i < NW1_) oa[i] = f2bf(a[i]);
  else if (i < NW1_ + NW3_) oc[i - NW1_] = f2bf(c[i - NW1_]);
  else if (i < NW1_ + NW3_ + NW2_) oe[i - NW1_ - NW3_] = f2bf(e[i - NW1_ - NW3_]);
  else if (i < NW1_ + NW3_ + NW2_ + NW4_)
    of[i - NW1_ - NW3_ - NW2_] = f2bf(f[i - NW1_ - NW3_ - NW2_]);
}

// --------- prep: transpose conv weights [l][e][4]->[l][4][e], A_log -> -exp, [l][s][e]
__global__ __launch_bounds__(256) void prep_kernel(const float* __restrict__ convw,
                                                   const float* __restrict__ A_log,
                                                   float* __restrict__ cwt,
                                                   float* __restrict__ At){
  int gid = blockIdx.x * 256 + threadIdx.x;      // NL_*DI_
  int l = gid >> 10, e = gid & (DI_ - 1);
  float4 cw = *(const float4*)(convw + (size_t)gid * 4);
  cwt[(l * 4 + 0) * DI_ + e] = cw.x;
  cwt[(l * 4 + 1) * DI_ + e] = cw.y;
  cwt[(l * 4 + 2) * DI_ + e] = cw.z;
  cwt[(l * 4 + 3) * DI_ + e] = cw.w;
  const float* ar = A_log + (size_t)gid * DS_;
#pragma unroll
  for (int s = 0; s < DS_; s++)
    At[((size_t)l * DS_ + s) * DI_ + e] = -__expf(ar[s]);
}

// ------- input projection: h = bf16(x @ ip_w^T + ip_b); w register-cached -------
__global__ __launch_bounds__(256) void inproj_kernel(const float* __restrict__ x,
                                                     const float* __restrict__ w,
                                                     const float* __restrict__ bias,
                                                     u16* __restrict__ h){
  __shared__ float xs[32 * DIN_];
  const int tid = threadIdx.x;
  const int m0 = blockIdx.x * 32;
  for (int i = tid; i < 32 * DIN_; i += 256) xs[i] = x[(size_t)m0 * DIN_ + i];
  float w0[DIN_], w1[DIN_];
  const int d0 = tid * 2;
#pragma unroll
  for (int i = 0; i < DIN_; i++){
    w0[i] = w[(size_t)d0 * DIN_ + i];
    w1[i] = w[(size_t)(d0 + 1) * DIN_ + i];
  }
  const float b0 = bias[d0], b1 = bias[d0 + 1];
  __syncthreads();
  for (int r = 0; r < 32; r++){
    float a0 = b0, a1 = b1;
    const float* xr = &xs[r * DIN_];
#pragma unroll
    for (int i = 0; i < DIN_; i++){
      float xv = xr[i];
      a0 = fmaf(xv, w0[i], a0);
      a1 = fmaf(xv, w1[i], a1);
    }
    unsigned int pk = ((unsigned int)f2bf(a1) << 16) | (unsigned int)f2bf(a0);
    *(unsigned int*)(h + (size_t)(m0 + r) * DM_ + d0) = pk;
  }
}

// ---------------- fused layernorm: bf16 h -> bf16 hn (stats + apply) ----------------
__global__ __launch_bounds__(256) void ln_kernel(const u16* __restrict__ h,
                                                 const float* __restrict__ g,
                                                 const float* __restrict__ bt,
                                                 u16* __restrict__ hn){
  int row = blockIdx.x * 4 + (threadIdx.x >> 6);
  int lane = threadIdx.x & 63;
  const u16* hr = h + (size_t)row * DM_ + lane * 8;
  ushort4 a0 = *(const ushort4*)(hr);
  ushort4 a1 = *(const ushort4*)(hr + 4);
  float v[8];
  v[0]=bf2f(a0.x); v[1]=bf2f(a0.y); v[2]=bf2f(a0.z); v[3]=bf2f(a0.w);
  v[4]=bf2f(a1.x); v[5]=bf2f(a1.y); v[6]=bf2f(a1.z); v[7]=bf2f(a1.w);
  float s = 0.f, q = 0.f;
#pragma unroll
  for (int i = 0; i < 8; i++){ s += v[i]; q += v[i]*v[i]; }
#pragma unroll
  for (int o = 32; o; o >>= 1){ s += __shfl_xor(s, o); q += __shfl_xor(q, o); }
  float mean = s * (1.f / DM_);
  float rstd = rsqrtf(q * (1.f / DM_) - mean * mean + 1e-5f);
  float4 g0 = *(const float4*)(g + lane * 8);
  float4 g1 = *(const float4*)(g + lane * 8 + 4);
  float4 b0 = *(const float4*)(bt + lane * 8);
  float4 b1 = *(const float4*)(bt + lane * 8 + 4);
  ushort4 o0, o1;
  o0.x = f2bf((v[0]-mean)*rstd*g0.x + b0.x);
  o0.y = f2bf((v[1]-mean)*rstd*g0.y + b0.y);
  o0.z = f2bf((v[2]-mean)*rstd*g0.z + b0.z);
  o0.w = f2bf((v[3]-mean)*rstd*g0.w + b0.w);
  o1.x = f2bf((v[4]-mean)*rstd*g1.x + b1.x);
  o1.y = f2bf((v[5]-mean)*rstd*g1.y + b1.y);
  o1.z = f2bf((v[6]-mean)*rstd*g1.z + b1.z);
  o1.w = f2bf((v[7]-mean)*rstd*g1.w + b1.w);
  u16* op = hn + (size_t)row * DM_ + lane * 8;
  *(ushort4*)(op)     = o0;
  *(ushort4*)(op + 4) = o1;
}

// ------- causal depthwise conv (DC=4) + SiLU, 8 ch/thread, transposed weights ------
__global__ __launch_bounds__(256) void conv8_kernel(const u16* __restrict__ xu,
                                                    const float* __restrict__ cwt,
                                                    const float* __restrict__ cbp,
                                                    u16* __restrict__ ub){
  int idx = blockIdx.x * 256 + threadIdx.x;      // over MC*DI/8
  int e8 = (idx & 127) * 8;
  int bl = idx >> 7;
  int l = bl & (L_ - 1);
  const u16* p = xu + (size_t)bl * DI_ + e8;
  float acc[8];
  {
    float4 c0 = *(const float4*)(cbp + e8);
    float4 c1 = *(const float4*)(cbp + e8 + 4);
    acc[0]=c0.x; acc[1]=c0.y; acc[2]=c0.z; acc[3]=c0.w;
    acc[4]=c1.x; acc[5]=c1.y; acc[6]=c1.z; acc[7]=c1.w;
  }
#pragma unroll
  for (int d = 0; d < 4; d++){
    if (l - 3 + d >= 0){
      const u16* q = p - (size_t)(3 - d) * DI_;
      ushort4 v0 = *(const ushort4*)q, v1 = *(const ushort4*)(q + 4);
      float4 w0 = *(const float4*)(cwt + d * DI_ + e8);
      float4 w1 = *(const float4*)(cwt + d * DI_ + e8 + 4);
      acc[0] += bf2f(v0.x) * w0.x; acc[1] += bf2f(v0.y) * w0.y;
      acc[2] += bf2f(v0.z) * w0.z; acc[3] += bf2f(v0.w) * w0.w;
      acc[4] += bf2f(v1.x) * w1.x; acc[5] += bf2f(v1.y) * w1.y;
      acc[6] += bf2f(v1.z) * w1.z; acc[7] += bf2f(v1.w) * w1.w;
    }
  }
  ushort4 h0, h1;
  h0.x = f2bf(siluf(acc[0])); h0.y = f2bf(siluf(acc[1]));
  h0.z = f2bf(siluf(acc[2])); h0.w = f2bf(siluf(acc[3]));
  h1.x = f2bf(siluf(acc[4])); h1.y = f2bf(siluf(acc[5]));
  h1.z = f2bf(siluf(acc[6])); h1.w = f2bf(siluf(acc[7]));
  u16* o = ub + (size_t)bl * DI_ + e8;
  *(ushort4*)o = h0;
  *(ushort4*)(o + 4) = h1;
}

// ---------------- GEMM: C[M][N] = A[M][K] (bf16) @ W[N][K]^T (bf16) ----------------
// TPB threads. global_load_lds staging (linear LDS dest + pre-swizzled source), swz
// read. 1D grid with XCD-locality swizzle. Direct scalar C stores (proven fastest
// tail for this 2-barrier structure; LDS-staged and packed variants both regressed).
// EPI 0: bf16 store. EPI 1: bf16(softplus(v + bias[n])). EPI 2: bf16(v + Res)
// (Cb may alias Res). EPI 4: n<nsplit -> Cb raw, else Cb2 silu (stride nsplit).
template<int BM, int BN, int BK, int EPI, int TPB>
__global__ __launch_bounds__(TPB)
void gemm_bt(const u16* __restrict__ A, int lda,
             const u16* __restrict__ Bw,
             u16* Cb, u16* Cb2, const u16* Res,
             const float* __restrict__ bias,
             int N, int K, int nsplit, int gx){
  constexpr int CH = BK / 8;
  constexpr int MASK = CH - 1;
  constexpr int WROWS = TPB / 128;     // 2 or 4
  constexpr int WM = BM / WROWS, WN = BN / 2;
  constexpr int FM = WM / 16, FN = WN / 16;
  __shared__ u16 As_[BM * BK];
  __shared__ u16 Bs_[BN * BK];
  const int tid = threadIdx.x;
  const int lane = tid & 63;
  const int wid = tid >> 6;
  const int wr = wid >> 1, wc = wid & 1;
  int bm, bn;
  {
    const int wg = blockIdx.x;
    const int gy = (int)gridDim.x / gx;
    const int ypx = gy >> 3;            // M-panels per XCD
    const int xcd = wg & 7;
    const int idx = wg >> 3;
    const int y = xcd * ypx + (idx % ypx);
    const int x = idx / ypx;
    bm = y * BM; bn = x * BN;
  }
  f32x4 acc[FM][FN];
#pragma unroll
  for (int i = 0; i < FM; i++)
#pragma unroll
    for (int j = 0; j < FN; j++) acc[i][j] = f32x4{0.f, 0.f, 0.f, 0.f};
  constexpr int LA = BM * BK / (TPB * 8);
  constexpr int LB = BN * BK / (TPB * 8);
  const int wbase = wid * 64;           // wave-uniform chunk base within a TPB-group
  for (int k0 = 0; k0 < K; k0 += BK){
    __syncthreads();
#pragma unroll
    for (int i = 0; i < LA; i++){
      int chunk = i * TPB + tid;
      int row = chunk / CH, cs = chunk & MASK;
      int cg = cs ^ (row & MASK);       // pre-swizzled global source chunk
      const u16* g = A + (size_t)(bm + row) * lda + k0 + cg * 8;
      gload_lds16(g, &As_[(i * TPB + wbase) * 8]);
    }
#pragma unroll
    for (int i = 0; i < LB; i++){
      int chunk = i * TPB + tid;
      int row = chunk / CH, cs = chunk & MASK;
      int cg = cs ^ (row & MASK);
      const u16* g = Bw + (size_t)(bn + row) * K + k0 + cg * 8;
      gload_lds16(g, &Bs_[(i * TPB + wbase) * 8]);
    }
    __syncthreads();
#pragma unroll
    for (int kk = 0; kk < BK / 32; kk++){
      bf16x8 af[FM], bfr[FN];
      const int kch = kk * 4 + (lane >> 4);
#pragma unroll
      for (int mi = 0; mi < FM; mi++){
        int r = wr * WM + mi * 16 + (lane & 15);
        af[mi] = *(const bf16x8*)(&As_[r * BK + ((kch ^ (r & MASK))) * 8]);
      }
#pragma unroll
      for (int ni = 0; ni < FN; ni++){
        int r = wc * WN + ni * 16 + (lane & 15);
        bfr[ni] = *(const bf16x8*)(&Bs_[r * BK + ((kch ^ (r & MASK))) * 8]);
      }
#pragma unroll
      for (int mi = 0; mi < FM; mi++)
#pragma unroll
        for (int ni = 0; ni < FN; ni++)
          acc[mi][ni] = __builtin_amdgcn_mfma_f32_16x16x32_bf16(af[mi], bfr[ni], acc[mi][ni], 0, 0, 0);
    }
  }
  const int rq = (lane >> 4) * 4, cl = lane & 15;
#pragma unroll
  for (int mi = 0; mi < FM; mi++){
#pragma unroll
    for (int ni = 0; ni < FN; ni++){
      const int n = bn + wc * WN + ni * 16 + cl;
#pragma unroll
      for (int j = 0; j < 4; j++){
        const int m = bm + wr * WM + mi * 16 + rq + j;
        float v = acc[mi][ni][j];
        if constexpr (EPI == 0){
          Cb[(size_t)m * N + n] = f2bf(v);
        } else if constexpr (EPI == 1){
          float xx = v + bias[n];
          float sp = (xx > 20.f) ? xx : __logf(1.f + __expf(xx));
          Cb[(size_t)m * N + n] = f2bf(sp);
        } else if constexpr (EPI == 2){
          const size_t off = (size_t)m * N + n;
          Cb[off] = f2bf(v + bf2f(Res[off]));
        } else {
          if (n < nsplit){
            Cb[(size_t)m * nsplit + n] = f2bf(v);
          } else {
            Cb2[(size_t)m * nsplit + (n - nsplit)] = f2bf(siluf(v));
          }
        }
      }
    }
  }
}

// ---------------- scan pass 1: per-chunk (sdd, h_part), h0 = 0 ----------------
// grid (DI/256, NCH, Bc); sdd_b[c][be] f32; h_b[c][be][16] f32
__global__ __launch_bounds__(256)
void scan1_kernel(const u16* __restrict__ ub, const u16* __restrict__ dlt,
                  const u16* __restrict__ xdb,
                  const float* __restrict__ At,
                  float* __restrict__ sdd_b, float* __restrict__ h_b){
  const int tid = threadIdx.x;
  const int e = blockIdx.x * 256 + tid;
  const int c = blockIdx.y, b = blockIdx.z;
  __shared__ float Bsh[CHT_][DS_];     // 2 KB
  if (tid < CHT_ * DS_ / 4){
    int row = tid >> 2, col4 = (tid & 3) * 4;
    const u16* p = xdb + ((size_t)b * L_ + (size_t)c * CHT_ + row) * 64 + 32 + col4;
    ushort4 v = *(const ushort4*)p;
    Bsh[row][col4+0] = bf2f(v.x); Bsh[row][col4+1] = bf2f(v.y);
    Bsh[row][col4+2] = bf2f(v.z); Bsh[row][col4+3] = bf2f(v.w);
  }
  __syncthreads();
  float As[DS_];
  bool fast = true;
#pragma unroll
  for (int s = 0; s < DS_; s++){
    As[s] = At[(size_t)s * DI_ + e];
    fast = fast && (fabsf(As[s] + (float)(s + 1)) <= 1e-3f * (s + 1));
  }
  float h[DS_];
#pragma unroll
  for (int s = 0; s < DS_; s++) h[s] = 0.f;
  float sdd = 0.f;
  const size_t base = ((size_t)b * L_ + (size_t)c * CHT_) * DI_ + e;
  if (fast){
    for (int t = 0; t < CHT_; t++){
      const size_t idx = base + (size_t)t * DI_;
      float ut = bf2f(ub[idx]);
      float delta = bf2f(dlt[idx]);
      sdd += delta;
      float du = delta * ut;
      float e1 = __expf(-delta);
      float e2 = e1*e1, e4 = e2*e2, e8 = e4*e4;
      float dA[DS_] = {e1, e2, e2*e1, e4, e4*e1, e4*e2, e4*e2*e1, e8,
                       e8*e1, e8*e2, e8*e2*e1, e8*e4, e8*e4*e1, e8*e4*e2,
                       e8*e4*e2*e1, e8*e8};
      const float* r = &Bsh[t][0];
#pragma unroll
      for (int s = 0; s < DS_; s++)
        h[s] = fmaf(dA[s], h[s], du * r[s]);
    }
  } else {
    for (int t = 0; t < CHT_; t++){
      const size_t idx = base + (size_t)t * DI_;
      float ut = bf2f(ub[idx]);
      float delta = bf2f(dlt[idx]);
      sdd += delta;
      float du = delta * ut;
      const float* r = &Bsh[t][0];
#pragma unroll
      for (int s = 0; s < DS_; s++)
        h[s] = fmaf(__expf(delta * As[s]), h[s], du * r[s]);
    }
  }
  const size_t be = (size_t)b * DI_ + e;
  sdd_b[(size_t)c * (BC_ * DI_) + be] = sdd;
  float* p = h_b + ((size_t)c * (BC_ * DI_) + be) * DS_;
#pragma unroll
  for (int s = 0; s < DS_; s++) p[s] = h[s];
}

// -------- scan pass 2: combine (a_prod recomputed from sdd) -> h_init per chunk -----
__global__ __launch_bounds__(256)
void scan2_kernel(const float* __restrict__ At,
                  const float* __restrict__ sdd_b, float* __restrict__ h_b){
  const int be = blockIdx.x * 256 + threadIdx.x;
  const int BE = BC_ * DI_;
  const int e = be & (DI_ - 1);
  float As[DS_];
  bool fast = true;
#pragma unroll
  for (int s = 0; s < DS_; s++){
    As[s] = At[(size_t)s * DI_ + e];
    fast = fast && (fabsf(As[s] + (float)(s + 1)) <= 1e-3f * (s + 1));
  }
  float h[DS_];
#pragma unroll
  for (int s = 0; s < DS_; s++) h[s] = 0.f;
  for (int c = 0; c < NCH_; c++){
    float sdd = sdd_b[(size_t)c * BE + be];
    float* p = h_b + ((size_t)c * BE + be) * DS_;
    float4 h0 = *(const float4*)(p);
    float4 h1 = *(const float4*)(p + 4);
    float4 h2 = *(const float4*)(p + 8);
    float4 h3 = *(const float4*)(p + 12);
    float hv[16] = {h0.x,h0.y,h0.z,h0.w, h1.x,h1.y,h1.z,h1.w,
                    h2.x,h2.y,h2.z,h2.w, h3.x,h3.y,h3.z,h3.w};
    float ap[DS_];
    if (fast){
      float e1 = __expf(-sdd);
      float e2 = e1*e1, e4 = e2*e2, e8 = e4*e4;
      ap[0]=e1; ap[1]=e2; ap[2]=e2*e1; ap[3]=e4; ap[4]=e4*e1; ap[5]=e4*e2;
      ap[6]=e4*e2*e1; ap[7]=e8; ap[8]=e8*e1; ap[9]=e8*e2; ap[10]=e8*e2*e1;
      ap[11]=e8*e4; ap[12]=e8*e4*e1; ap[13]=e8*e4*e2; ap[14]=e8*e4*e2*e1;
      ap[15]=e8*e8;
    } else {
#pragma unroll
      for (int s = 0; s < DS_; s++) ap[s] = __expf(As[s] * sdd);
    }
    float4 w0, w1, w2, w3;
    float* wv[4] = {&w0.x, &w1.x, &w2.x, &w3.x};
#pragma unroll
    for (int s = 0; s < DS_; s++){
      float hi = h[s];
      h[s] = ap[s] * hi + hv[s];
      wv[s >> 2][s & 3] = hi;
    }
    *(float4*)(p)      = w0;
    *(float4*)(p + 4)  = w1;
    *(float4*)(p + 8)  = w2;
    *(float4*)(p + 12) = w3;
  }
}

// ---------------- scan pass 3: rescan + gate; y over silu(z) in place --------------
__global__ __launch_bounds__(256)
void scan3_kernel(const u16* __restrict__ ub, const u16* __restrict__ dlt,
                  u16* __restrict__ zy, const u16* __restrict__ xdb,
                  const float* __restrict__ At, const float* __restrict__ Dp,
                  const float* __restrict__ h_b){
  const int tid = threadIdx.x;
  const int e = blockIdx.x * 256 + tid;
  const int c = blockIdx.y, b = blockIdx.z;
  __shared__ float BC[CHT_][32];       // 4 KB: B | C
  {
    int row = tid >> 3, col4 = (tid & 7) * 4;
    const u16* p = xdb + ((size_t)b * L_ + (size_t)c * CHT_ + row) * 64 + 32 + col4;
    ushort4 v = *(const ushort4*)p;
    BC[row][col4+0] = bf2f(v.x); BC[row][col4+1] = bf2f(v.y);
    BC[row][col4+2] = bf2f(v.z); BC[row][col4+3] = bf2f(v.w);
  }
  __syncthreads();
  float As[DS_];
  bool fast = true;
#pragma unroll
  for (int s = 0; s < DS_; s++){
    As[s] = At[(size_t)s * DI_ + e];
    fast = fast && (fabsf(As[s] + (float)(s + 1)) <= 1e-3f * (s + 1));
  }
  const float Dv = Dp[e];
  const float* ip = h_b + ((size_t)c * (BC_ * DI_) + (size_t)b * DI_ + e) * DS_;
  float h[DS_];
#pragma unroll
  for (int s = 0; s < DS_; s++) h[s] = ip[s];
  const size_t base = ((size_t)b * L_ + (size_t)c * CHT_) * DI_ + e;
  if (fast){
    for (int t = 0; t < CHT_; t++){
      const size_t idx = base + (size_t)t * DI_;
      float ut = bf2f(ub[idx]);
      float delta = bf2f(dlt[idx]);
      float du = delta * ut;
      float e1 = __expf(-delta);
      float e2 = e1*e1, e4 = e2*e2, e8 = e4*e4;
      float dA[DS_] = {e1, e2, e2*e1, e4, e4*e1, e4*e2, e4*e2*e1, e8,
                       e8*e1, e8*e2, e8*e2*e1, e8*e4, e8*e4*e1, e8*e4*e2,
                       e8*e4*e2*e1, e8*e8};
      const float* r = &BC[t][0];
      float yv = 0.f;
#pragma unroll
      for (int s = 0; s < DS_; s++){
        h[s] = fmaf(dA[s], h[s], du * r[s]);
        yv = fmaf(h[s], r[16 + s], yv);
      }
      float zs = bf2f(zy[idx]);
      zy[idx] = f2bf((yv + ut * Dv) * zs);
    }
  } else {
    for (int t = 0; t < CHT_; t++){
      const size_t idx = base + (size_t)t * DI_;
      float ut = bf2f(ub[idx]);
      float delta = bf2f(dlt[idx]);
      float du = delta * ut;
      const float* r = &BC[t][0];
      float yv = 0.f;
#pragma unroll
      for (int s = 0; s < DS_; s++){
        h[s] = fmaf(__expf(delta * As[s]), h[s], du * r[s]);
        yv = fmaf(h[s], r[16 + s], yv);
      }
      float zs = bf2f(zy[idx]);
      zy[idx] = f2bf((yv + ut * Dv) * zs);
    }
  }
}

// ---------------- mean-pool partials over L ----------------
__global__ __launch_bounds__(256) void pool_kernel(const u16* __restrict__ h,
                                                   float* __restrict__ part){
  int d = blockIdx.x * 256 + threadIdx.x;
  int b = blockIdx.y;
  int p = blockIdx.z;
  float s = 0.f;
  const u16* hp = h + ((size_t)b * L_ + p * 128) * DM_ + d;
  for (int l = 0; l < 128; l++) s += bf2f(hp[(size_t)l * DM_]);
  part[((size_t)p * B_ + b) * DM_ + d] = s;
}

// ---------------- final FC ----------------
__global__ __launch_bounds__(256) void fc_kernel(const float* __restrict__ part,
                                                 const float* __restrict__ fcw,
                                                 const float* __restrict__ fcb,
                                                 float* __restrict__ out){
  int b = blockIdx.x;
  int tid = threadIdx.x;
  __shared__ float pd[DM_];
  for (int d = tid; d < DM_; d += 256){
    float s = 0.f;
    for (int p = 0; p < 8; p++) s += part[((size_t)p * B_ + b) * DM_ + d];
    pd[d] = s * (1.f / L_);
  }
  __syncthreads();
  int wid = tid >> 6, lane = tid & 63;
  for (int c = wid; c < NC_; c += 4){
    float s = 0.f;
    for (int d = lane; d < DM_; d += 64) s += pd[d] * fcw[c * DM_ + d];
#pragma unroll
    for (int o = 32; o; o >>= 1) s += __shfl_xor(s, o);
    if (lane == 0) out[b * NC_ + c] = s + fcb[c];
  }
}

extern "C" void kernel_launch(void* const* d_in, const int* in_sizes, int n_in,
                              void* d_out, int out_size, void* d_ws, size_t ws_size,
                              hipStream_t stream){
  const float* x     = (const float*)d_in[0];
  const float* ip_w  = (const float*)d_in[1];
  const float* ip_b  = (const float*)d_in[2];
  const float* ln_g  = (const float*)d_in[3];
  const float* ln_b  = (const float*)d_in[4];
  const float* inpw  = (const float*)d_in[5];
  const float* convw = (const float*)d_in[6];
  const float* convb = (const float*)d_in[7];
  const float* xpw   = (const float*)d_in[8];
  const float* dtw   = (const float*)d_in[9];
  const float* dtb   = (const float*)d_in[10];
  const float* Alog  = (const float*)d_in[11];
  const float* Dp    = (const float*)d_in[12];
  const float* outw  = (const float*)d_in[13];
  const float* fcw   = (const float*)d_in[14];
  const float* fcb   = (const float*)d_in[15];
  float* out = (float*)d_out;

  char* ws = (char*)d_ws;
  size_t off = 0;
  auto alloc = [&](size_t bytes) -> void* {
    void* p = ws + off; off += (bytes + 255) & ~(size_t)255; return p;
  };
  // total ~212 MB (ws_size >= ~217 MB established in round 8; < 238 from round 4)
  u16*    h16   = (u16*)   alloc((size_t)M_ * DM_ * 2);          // 32 MB
  float*  part  = (float*) alloc((size_t)8 * B_ * DM_ * 4);      // 0.5 MB
  u16*    w_in  = (u16*)   alloc((size_t)NW1_ * 2);              // 8.4 MB
  u16*    w_out = (u16*)   alloc((size_t)NW3_ * 2);              // 4.2 MB
  u16*    w_xp  = (u16*)   alloc((size_t)NW2_ * 2);              // 0.5 MB
  u16*    w_dt  = (u16*)   alloc((size_t)NW4_ * 2);              // 0.26 MB
  float*  cwt   = (float*) alloc((size_t)NL_ * 4 * DI_ * 4);     // 64 KB
  float*  At    = (float*) alloc((size_t)NL_ * DS_ * DI_ * 4);   // 256 KB
  u16*    xu    = (u16*)   alloc((size_t)MC_ * DI_ * 2);         // 32 MB u_pre
  u16*    ub    = (u16*)   alloc((size_t)MC_ * DI_ * 2);         // 32 MB u
  u16*    xzs   = (u16*)   alloc((size_t)MC_ * DI_ * 2);         // 32 MB silu(z)->y
  u16*    dlt   = (u16*)   alloc((size_t)MC_ * DI_ * 2);         // 32 MB hn, then delta
  u16*    xdb   = (u16*)   alloc((size_t)MC_ * 64 * 2);          // 2 MB dt_in|B|C
  float*  sddb  = (float*) alloc((size_t)NCH_ * BC_ * DI_ * 4);      // 2 MB
  float*  hb    = (float*) alloc((size_t)NCH_ * BC_ * DI_ * DS_ * 4); // 33.5 MB
  u16*    hn    = dlt;     // alias: hn lives in dlt until dt GEMM overwrites it

  cast4_kernel<<<(NW1_ + NW3_ + NW2_ + NW4_ + 255) / 256, 256, 0, stream>>>(
      inpw, outw, xpw, dtw, w_in, w_out, w_xp, w_dt);
  prep_kernel<<<(NL_ * DI_) / 256, 256, 0, stream>>>(convw, Alog, cwt, At);
  inproj_kernel<<<M_ / 32, 256, 0, stream>>>(x, ip_w, ip_b, h16);

  const int GY64 = MC_ / 64;  // 256 M-panels (64-row tiles; multiple of 8)
  const int GY2  = MC_ / 256; // 64 M-panels (256-row tiles; multiple of 8)
  for (int i = 0; i < NL_; i++){
    const float* At_l = At + (size_t)i * DS_ * DI_;
    for (int c = 0; c < NCC_; c++){
      u16* hc = h16 + (size_t)c * MC_ * DM_;

      // fused LN (stats + apply), hn materialized in dlt buffer
      ln_kernel<<<MC_ / 4, 256, 0, stream>>>(hc, ln_g + i * DM_, ln_b + i * DM_, hn);

      // in-proj 256x128 tile, 512 thr; split epi: xu = u_pre, xzs = silu(z) (gx=16)
      gemm_bt<256, 128, 64, 4, 512><<<16 * GY2, 512, 0, stream>>>(
          hn, DM_, w_in + (size_t)i * 2 * DI_ * DM_, xu, xzs, nullptr, nullptr,
          2 * DI_, DM_, DI_, 16);

      // u = silu(causal_conv(u_pre)), transposed weights, materialized once
      conv8_kernel<<<(MC_ * DI_ / 8) / 256, 256, 0, stream>>>(
          xu, cwt + (size_t)i * 4 * DI_, convb + i * DI_, ub);

      // x_dbl = u @ xpw^T  (N=64: dt_in | B | C)  64-row tile -> 256 blocks (gx=1)
      gemm_bt<64, 64, 64, 0, 256><<<1 * GY64, 256, 0, stream>>>(
          ub, DI_, w_xp + (size_t)i * 64 * DI_, xdb, nullptr, nullptr, nullptr,
          64, DI_, 0, 1);

      // delta = softplus(x_dbl[:, :32] @ dtw^T + dt_b)  256x128, 512 thr (gx=8)
      gemm_bt<256, 128, 32, 1, 512><<<8 * GY2, 512, 0, stream>>>(
          xdb, 64, w_dt + (size_t)i * DI_ * DTR_, dlt, nullptr, nullptr,
          dtb + i * DI_, DI_, DTR_, 0, 8);

      // chunk-parallel scan (NCH=32 -> 2048 blocks, 8 waves/SIMD)
      scan1_kernel<<<dim3(DI_ / 256, NCH_, BC_), 256, 0, stream>>>(
          ub, dlt, xdb, At_l, sddb, hb);
      scan2_kernel<<<(BC_ * DI_) / 256, 256, 0, stream>>>(At_l, sddb, hb);
      scan3_kernel<<<dim3(DI_ / 256, NCH_, BC_), 256, 0, stream>>>(
          ub, dlt, xzs, xdb, At_l, Dp + i * DI_, hb);

      // h += y_gated @ out_w^T  256x128 tile (gx = 4)
      gemm_bt<256, 128, 64, 2, 512><<<4 * GY2, 512, 0, stream>>>(
          xzs, DI_, w_out + (size_t)i * DM_ * DI_, hc, nullptr, hc,
          nullptr, DM_, DI_, 0, 4);
    }
  }

  pool_kernel<<<dim3(2, B_, 8), 256, 0, stream>>>(h16, part);
  fc_kernel<<<B_, 256, 0, stream>>>(part, fcw, fcb, out);
}